// Round 1
// baseline (1520.121 us; speedup 1.0000x reference)
//
#include <hip/hip_runtime.h>

typedef _Float16 f16;
typedef _Float16 f16x2 __attribute__((ext_vector_type(2)));
typedef _Float16 f16x8 __attribute__((ext_vector_type(8)));
typedef float f32x4 __attribute__((ext_vector_type(4)));
typedef unsigned int u32;
typedef unsigned short u16;

#define B_SZ 64
#define T_SZ 512
#define DIN 768
#define H_SZ 256
#define TH 768               // 3*H
#define M_ROWS (B_SZ * T_SZ) // 32768

// Workspace layout (bytes). Total = 69,861,376 B (~66.6 MB).
#define O_WT1 ((size_t)0)
#define O_WT2 (O_WT1 + (size_t)768 * 768 * 2)
#define O_H1 (O_WT2 + (size_t)768 * 1024 * 2)
#define O_G (O_H1 + (size_t)M_ROWS * H_SZ * 2)

__device__ __forceinline__ u32 pk2(float a, float b) {
  union { f16 h[2]; u32 u; } x;
  x.h[0] = (f16)a;
  x.h[1] = (f16)b;
  return x.u;
}

__device__ __forceinline__ float dot2f(u32 w, u32 h, float acc) {
#if __has_builtin(__builtin_amdgcn_fdot2)
  union { u32 u; f16x2 v; } a, b;
  a.u = w;
  b.u = h;
  return __builtin_amdgcn_fdot2(a.v, b.v, acc, false);
#else
  union { u32 u; f16 h[2]; } a, b;
  a.u = w;
  b.u = h;
  acc = fmaf((float)a.h[0], (float)b.h[0], acc);
  acc = fmaf((float)a.h[1], (float)b.h[1], acc);
  return acc;
#endif
}

__device__ __forceinline__ float sigmf_(float x) {
  return 1.0f / (1.0f + __expf(-x));
}
__device__ __forceinline__ float tanhf_(float x) {
  float e = __expf(-2.0f * fabsf(x));
  float r = (1.0f - e) / (1.0f + e);
  return copysignf(r, x);
}

// ---------------------------------------------------------------------------
// Transpose+convert: W [K][N] fp32 -> Wt [N][K] fp16
// ---------------------------------------------------------------------------
__global__ __launch_bounds__(256) void k_transpose(const float* __restrict__ W,
                                                   f16* __restrict__ Wt, int K,
                                                   int N) {
  __shared__ f16 tile[32][33];
  int tx = threadIdx.x, ty = threadIdx.y;
  int n0 = blockIdx.x * 32, k0 = blockIdx.y * 32;
#pragma unroll
  for (int q = 0; q < 4; ++q) {
    int k = k0 + ty + q * 8;
    tile[ty + q * 8][tx] = (f16)W[(size_t)k * N + n0 + tx];
  }
  __syncthreads();
#pragma unroll
  for (int q = 0; q < 4; ++q) {
    int n = n0 + ty + q * 8;
    Wt[(size_t)n * K + k0 + tx] = tile[tx][ty + q * 8];
  }
}

// ---------------------------------------------------------------------------
// fp16 MFMA GEMM: C[M][768] = A @ Bt^T + bias.
// A: rows from A32 (fp32, k<768, converted on stage) and/or AH (fp16, k>=768).
// Bt: [768 n][K k] fp16 (pre-transposed weights). Tile 128x128, BK=32.
// ---------------------------------------------------------------------------
#define LDK 40 // padded LDS k-stride (halves); 80 B rows -> 2-way banks (free)
__global__ __launch_bounds__(256, 2) void k_gemm(
    const float* __restrict__ A32, const f16* __restrict__ AH,
    const f16* __restrict__ Bt, const float* __restrict__ bias,
    f16* __restrict__ C, int K, int bstride) {
  __shared__ __align__(16) f16 Asm[128 * LDK];
  __shared__ __align__(16) f16 Bsm[128 * LDK];
  int tid = threadIdx.x;
  int lane = tid & 63, wave = tid >> 6;
  int wm = wave & 1, wn = wave >> 1;
  int fm = lane & 15, fk = (lane >> 4) * 8;
  int srow = tid >> 1, skp = (tid & 1) * 16;
  size_t r0 = (size_t)blockIdx.y * 128;
  int n0 = blockIdx.x * 128;
  f32x4 acc[4][4] = {};

  for (int k0 = 0; k0 < K; k0 += 32) {
    __syncthreads();
    // Stage A-tile (128 x 32 halves): 2 threads/row, 16 halves each.
    if (k0 < DIN) {
      const float* src = A32 + (r0 + srow) * DIN + k0 + skp;
      float4 v0 = *(const float4*)(src);
      float4 v1 = *(const float4*)(src + 4);
      float4 v2 = *(const float4*)(src + 8);
      float4 v3 = *(const float4*)(src + 12);
      uint4 w0 = make_uint4(pk2(v0.x, v0.y), pk2(v0.z, v0.w), pk2(v1.x, v1.y),
                            pk2(v1.z, v1.w));
      uint4 w1 = make_uint4(pk2(v2.x, v2.y), pk2(v2.z, v2.w), pk2(v3.x, v3.y),
                            pk2(v3.z, v3.w));
      *(uint4*)&Asm[srow * LDK + skp] = w0;
      *(uint4*)&Asm[srow * LDK + skp + 8] = w1;
    } else {
      const uint4* src =
          (const uint4*)(AH + (r0 + srow) * H_SZ + (k0 - DIN) + skp);
      *(uint4*)&Asm[srow * LDK + skp] = src[0];
      *(uint4*)&Asm[srow * LDK + skp + 8] = src[1];
    }
    // Stage B-tile (128 n x 32 k halves) from pre-transposed fp16 weights.
    const uint4* bsrc =
        (const uint4*)(Bt + (size_t)(n0 + srow) * bstride + k0 + skp);
    *(uint4*)&Bsm[srow * LDK + skp] = bsrc[0];
    *(uint4*)&Bsm[srow * LDK + skp + 8] = bsrc[1];
    __syncthreads();

    f16x8 af[4], bf[4];
#pragma unroll
    for (int mt = 0; mt < 4; ++mt)
      af[mt] = *(const f16x8*)&Asm[(wm * 64 + mt * 16 + fm) * LDK + fk];
#pragma unroll
    for (int nt = 0; nt < 4; ++nt)
      bf[nt] = *(const f16x8*)&Bsm[(wn * 64 + nt * 16 + fm) * LDK + fk];
#pragma unroll
    for (int mt = 0; mt < 4; ++mt)
#pragma unroll
      for (int nt = 0; nt < 4; ++nt)
        acc[mt][nt] = __builtin_amdgcn_mfma_f32_16x16x32_f16(af[mt], bf[nt],
                                                             acc[mt][nt], 0, 0, 0);
  }

  // Epilogue: C/D layout col=lane&15, row=(lane>>4)*4+reg (dtype-independent).
  int ccol = lane & 15, crb = (lane >> 4) * 4;
#pragma unroll
  for (int nt = 0; nt < 4; ++nt) {
    int col = n0 + wn * 64 + nt * 16 + ccol;
    float bv = bias[col];
#pragma unroll
    for (int mt = 0; mt < 4; ++mt) {
      size_t rb = r0 + wm * 64 + mt * 16 + crb;
#pragma unroll
      for (int rg = 0; rg < 4; ++rg)
        C[(rb + rg) * TH + col] = (f16)(acc[mt][nt][rg] + bv);
    }
  }
}

// ---------------------------------------------------------------------------
// Recurrence: one workgroup (512 thr) per batch row. W_hh held in registers
// as packed fp16 pairs; h in LDS (fp32 state + fp16 pairs for v_dot2).
// Thread (cg, kh): cols {cg, cg+256, cg+512}, k-half [kh*128, kh*128+128).
// ---------------------------------------------------------------------------
__global__ __launch_bounds__(512, 2) void k_rec(
    const f16* __restrict__ G, const float* __restrict__ Whh,
    const float* __restrict__ bhh, const float* __restrict__ tau,
    float* __restrict__ out, int out_off, f16* __restrict__ H1out) {
  __shared__ __align__(16) u16 s_h16[256];
  __shared__ float s_h32[256];
  __shared__ float s_part[256 * 3];
  __shared__ __align__(16) f16 s_stage[32 * TH]; // 48 KB staging for weights

  int tid = threadIdx.x;
  int b = blockIdx.x;
  int cg = tid & 255;
  int kh = tid >> 8; // 0 or 1 (wave-uniform)

  // --- Load W_hh into registers: 3 cols x 64 packed pairs = 192 VGPRs ---
  u32 w2[3][64];
#pragma unroll
  for (int ch = 0; ch < 8; ++ch) {
    int kc = ch * 32;
    __syncthreads();
#pragma unroll
    for (int q = 0; q < 12; ++q) {
      int idx4 = tid + q * 512; // 6144 float4 = 32*768 floats
      float4 v = *(const float4*)(Whh + (size_t)kc * TH + (size_t)idx4 * 4);
      union { f16 h[4]; uint2 u; } pw;
      pw.h[0] = (f16)v.x;
      pw.h[1] = (f16)v.y;
      pw.h[2] = (f16)v.z;
      pw.h[3] = (f16)v.w;
      *(uint2*)&s_stage[idx4 * 4] = pw.u;
    }
    __syncthreads();
    if ((kc >> 7) == kh) { // this chunk belongs to my k-half
      int ib = (kc & 127) >> 1;
#pragma unroll
      for (int i2 = 0; i2 < 16; ++i2) {
#pragma unroll
        for (int c = 0; c < 3; ++c) {
          int col = cg + c * 256;
          w2[c][ib + i2] = pk2((float)s_stage[(2 * i2) * TH + col],
                               (float)s_stage[(2 * i2 + 1) * TH + col]);
        }
      }
    }
  }

  float bb0 = bhh[cg], bb1 = bhh[cg + 256], bb2 = bhh[cg + 512];
  float invt = 1.0f / tau[0];
  float om = 1.0f - invt;
  if (tid < 256) {
    s_h16[tid] = 0;
    s_h32[tid] = 0.0f;
  }
  __syncthreads();

  const f16* gbase = G + (size_t)b * T_SZ * TH;
  float* obase = out + (size_t)b * T_SZ * 512 + out_off;
  f16* hbase = H1out ? H1out + (size_t)b * T_SZ * H_SZ : (f16*)0;
  const uint4* hv4 = (const uint4*)s_h16 + kh * 16;

  for (int t = 0; t < T_SZ; ++t) {
    // Prefetch gi for this step (independent of h -> overlaps the dot loop).
    f16 gg0 = (f16)0.f, gg1 = (f16)0.f, gg2 = (f16)0.f;
    if (tid < 256) {
      const f16* gp = gbase + (size_t)t * TH + cg;
      gg0 = gp[0];
      gg1 = gp[256];
      gg2 = gp[512];
    }
    // gh partial dots over my k-half (h pairs broadcast from LDS).
    float a0 = 0.f, a1 = 0.f, a2 = 0.f;
#pragma unroll
    for (int ii = 0; ii < 16; ++ii) {
      uint4 hv = hv4[ii];
      a0 = dot2f(w2[0][ii * 4 + 0], hv.x, a0);
      a1 = dot2f(w2[1][ii * 4 + 0], hv.x, a1);
      a2 = dot2f(w2[2][ii * 4 + 0], hv.x, a2);
      a0 = dot2f(w2[0][ii * 4 + 1], hv.y, a0);
      a1 = dot2f(w2[1][ii * 4 + 1], hv.y, a1);
      a2 = dot2f(w2[2][ii * 4 + 1], hv.y, a2);
      a0 = dot2f(w2[0][ii * 4 + 2], hv.z, a0);
      a1 = dot2f(w2[1][ii * 4 + 2], hv.z, a1);
      a2 = dot2f(w2[2][ii * 4 + 2], hv.z, a2);
      a0 = dot2f(w2[0][ii * 4 + 3], hv.w, a0);
      a1 = dot2f(w2[1][ii * 4 + 3], hv.w, a1);
      a2 = dot2f(w2[2][ii * 4 + 3], hv.w, a2);
    }
    if (kh) {
      s_part[cg * 3 + 0] = a0;
      s_part[cg * 3 + 1] = a1;
      s_part[cg * 3 + 2] = a2;
    }
    __syncthreads();
    if (tid < 256) {
      float ghr = a0 + s_part[cg * 3 + 0] + bb0;
      float ghz = a1 + s_part[cg * 3 + 1] + bb1;
      float ghn = a2 + s_part[cg * 3 + 2] + bb2;
      float r = sigmf_((float)gg0 + ghr);
      float z = sigmf_((float)gg1 + ghz);
      float n = tanhf_((float)gg2 + r * ghn);
      float hold = s_h32[cg];
      float hc = (1.0f - z) * n + z * hold;
      float hn2 = om * hold + invt * hc;
      s_h32[cg] = hn2;
      union { f16 h; u16 s; } hb;
      hb.h = (f16)hn2;
      s_h16[cg] = hb.s;
      obase[(size_t)t * 512 + cg] = hn2;
      if (hbase) hbase[(size_t)t * H_SZ + cg] = (f16)hn2;
    }
    __syncthreads();
  }
}

// ---------------------------------------------------------------------------
extern "C" void kernel_launch(void* const* d_in, const int* in_sizes, int n_in,
                              void* d_out, int out_size, void* d_ws,
                              size_t ws_size, hipStream_t stream) {
  const float* enc = (const float*)d_in[0];
  const float* tau1 = (const float*)d_in[1];
  const float* tau2 = (const float*)d_in[2];
  const float* Wih1 = (const float*)d_in[3];
  const float* Whh1 = (const float*)d_in[4];
  const float* bih1 = (const float*)d_in[5];
  const float* bhh1 = (const float*)d_in[6];
  const float* Wih2 = (const float*)d_in[7];
  const float* Whh2 = (const float*)d_in[8];
  const float* bih2 = (const float*)d_in[9];
  const float* bhh2 = (const float*)d_in[10];
  float* out = (float*)d_out;
  char* ws = (char*)d_ws;

  f16* Wt1 = (f16*)(ws + O_WT1); // [768 n][768 k]
  f16* Wt2 = (f16*)(ws + O_WT2); // [768 n][1024 k]
  f16* H1 = (f16*)(ws + O_H1);   // [32768][256] h1 seq, fp16
  f16* G = (f16*)(ws + O_G);     // [32768][768] gi buffer (reused layer1/2)

  // Weight transposes (fp32 [k][n] -> fp16 [n][k]).
  k_transpose<<<dim3(24, 24), dim3(32, 8), 0, stream>>>(Wih1, Wt1, 768, 768);
  k_transpose<<<dim3(24, 32), dim3(32, 8), 0, stream>>>(Wih2, Wt2, 1024, 768);

  // Layer 1: gi1 = X @ W_ih1 + b_ih1, then recurrence.
  k_gemm<<<dim3(6, 256), 256, 0, stream>>>(enc, (const f16*)0, Wt1, bih1, G,
                                           768, 768);
  k_rec<<<64, 512, 0, stream>>>(G, Whh1, bhh1, tau1, out, 0, H1);

  // Layer 2: gi2 = [X | H1] @ W_ih2 + b_ih2, then recurrence.
  k_gemm<<<dim3(6, 256), 256, 0, stream>>>(enc, H1, Wt2, bih2, G, 1024, 1024);
  k_rec<<<64, 512, 0, stream>>>(G, Whh2, bhh2, tau2, out, 256, (f16*)0);
}